// Round 3
// baseline (433.649 us; speedup 1.0000x reference)
//
#include <hip/hip_runtime.h>
#include <hip/hip_cooperative_groups.h>

namespace cg = cooperative_groups;

#define HIDDEN 128
#define MIX 8
#define CAP 128   // bin capacity per node; degrees ~Poisson(32), max@N=10k ~65

// ---- Wnode GEMM tiling params ----
#define NBW 32   // nodes per block
#define LDX 33   // xs row stride
#define KT  16   // k-slab width for W_A
#define LDW 17   // wa slab row stride
#define LDG 132  // gsm/wb row stride (132%32=4, float4-aligned)

typedef float v2f __attribute__((ext_vector_type(2)));

__device__ __forceinline__ float gelu_exact(float x) {
    return 0.5f * x * (1.0f + erff(x * 0.7071067811865476f));
}

// ---------------- fused cooperative kernel ----------------
// phase 0: zero cursor                      (replaces hipMemsetAsync)
// phase 1: blocks [0,WB) Wnode GEMM ; blocks [WB,G) histogram+bins+echo
// phase 2: grid-strided wave-per-node aggregate + per-edge output
// LDS: union{ {xs,wa} , gsm } + wb = 20.6 KB -> 7 blocks/CU by LDS.
__global__ __launch_bounds__(256) void k_fused(
        const float* __restrict__ X,
        const float* __restrict__ W_A,
        const float* __restrict__ W_B,
        const int* __restrict__ src,
        const int* __restrict__ dst,
        float* __restrict__ Wnode,
        int* __restrict__ cursor,
        int2* __restrict__ bins,
        float* __restrict__ out_src,
        float* __restrict__ out_dst,
        float* __restrict__ out_edge,
        int N, int E, int WB) {
    cg::grid_group grid = cg::this_grid();
    int t = threadIdx.x;
    int b = blockIdx.x;
    int G = gridDim.x;

    __shared__ union SmemU {
        struct { float xs[NBW * LDX]; float wa[HIDDEN * LDW]; } ab;
        float gsm[NBW * LDG];
    } u;
    __shared__ float wb[MIX * LDG];

    // ---- phase 0: zero cursor ----
    for (int i = b * 256 + t; i < N; i += G * 256) cursor[i] = 0;
    grid.sync();

    // ---- phase 1 ----
    if (b < WB) {
        // Wnode[n][m] = sum_k gelu(X[n]·W_A[k,:]) * W_B[m][k]
        int n0 = b * NBW;

        {   // stage X rows: r = t>>3 (0..31), cols (t&7)*16 .. +15
            int r = t >> 3;
            int c0 = (t & 7) * 16;
            int rn = n0 + r; if (rn >= N) rn = N - 1;
            const float* xp = X + (size_t)rn * HIDDEN + c0;
            float4 a = ((const float4*)xp)[0];
            float4 bb = ((const float4*)xp)[1];
            float4 c = ((const float4*)xp)[2];
            float4 d = ((const float4*)xp)[3];
            float tmp[16] = {a.x,a.y,a.z,a.w, bb.x,bb.y,bb.z,bb.w,
                             c.x,c.y,c.z,c.w, d.x,d.y,d.z,d.w};
#pragma unroll
            for (int q = 0; q < 16; ++q) u.ab.xs[r * LDX + c0 + q] = tmp[q];
        }

        int ngrp = t & 7;    // 8 groups x 4 nodes
        int jgrp = t >> 3;   // 32 groups x 4 j
        float acc[4][4];
#pragma unroll
        for (int i = 0; i < 4; ++i)
#pragma unroll
            for (int j = 0; j < 4; ++j) acc[i][j] = 0.f;

        for (int kt = 0; kt < HIDDEN; kt += KT) {
            __syncthreads();  // protect wa (and xs on first iter)
            {   // stage W_A slab: j = t>>1 (0..127), cols kt + (t&1)*8 .. +7
                int j = t >> 1;
                int c0 = (t & 1) * 8;
                const float* wp = W_A + (size_t)j * HIDDEN + kt + c0;
                float4 a = ((const float4*)wp)[0];
                float4 bb = ((const float4*)wp)[1];
                float tmp[8] = {a.x,a.y,a.z,a.w, bb.x,bb.y,bb.z,bb.w};
#pragma unroll
                for (int q = 0; q < 8; ++q) u.ab.wa[j * LDW + c0 + q] = tmp[q];
            }
            __syncthreads();
#pragma unroll
            for (int k = 0; k < KT; ++k) {
                float xv[4], wv[4];
#pragma unroll
                for (int i = 0; i < 4; ++i) xv[i] = u.ab.xs[(ngrp * 4 + i) * LDX + kt + k];
#pragma unroll
                for (int j = 0; j < 4; ++j) wv[j] = u.ab.wa[(jgrp * 4 + j) * LDW + k];
#pragma unroll
                for (int i = 0; i < 4; ++i)
#pragma unroll
                    for (int j = 0; j < 4; ++j) acc[i][j] += xv[i] * wv[j];
            }
        }
        __syncthreads();  // xs/wa reads done; gsm aliases them

        // gelu -> gsm[n][j]
#pragma unroll
        for (int i = 0; i < 4; ++i)
#pragma unroll
            for (int j = 0; j < 4; ++j)
                u.gsm[(ngrp * 4 + i) * LDG + (jgrp * 4 + j)] = gelu_exact(acc[i][j]);

        // stage W_B (8 x 128)
        if (t < 64) {
            int r = t >> 3;
            int c0 = (t & 7) * 16;
            const float* wp = W_B + (size_t)r * HIDDEN + c0;
            float4 a = ((const float4*)wp)[0];
            float4 bb = ((const float4*)wp)[1];
            float4 c = ((const float4*)wp)[2];
            float4 d = ((const float4*)wp)[3];
            float tmp[16] = {a.x,a.y,a.z,a.w, bb.x,bb.y,bb.z,bb.w,
                             c.x,c.y,c.z,c.w, d.x,d.y,d.z,d.w};
#pragma unroll
            for (int q = 0; q < 16; ++q) wb[r * LDG + c0 + q] = tmp[q];
        }
        __syncthreads();

        // phase B: thread t -> n = t>>3, m = t&7
        {
            int n = t >> 3;
            int m = t & 7;
            float a = 0.f;
#pragma unroll 8
            for (int k = 0; k < HIDDEN; ++k)
                a += u.gsm[n * LDG + k] * wb[m * LDG + k];
            if (n0 + n < N) Wnode[(size_t)n0 * MIX + t] = a;
        }
    } else {
        // histogram + direct bin fill + echo, grid-strided
        for (int e = (b - WB) * 256 + t; e < E; e += (G - WB) * 256) {
            int d = dst[e];
            int s = src[e];
            int p = atomicAdd(&cursor[d], 1);
            if (p < CAP) bins[(size_t)d * CAP + p] = make_int2(e, s);
            __builtin_nontemporal_store((float)s, &out_src[e]);
            __builtin_nontemporal_store((float)d, &out_dst[e]);
        }
    }
    grid.sync();

    // ---- phase 2: wave-per-node, grid-strided ----
    int lane = t & 63;
    int wid = t >> 6;
    for (int n = b * 4 + wid; n < N; n += G * 4) {
        int cnt = cursor[n];
        if (cnt > CAP) cnt = CAP;   // overflow guard (unreachable for this dist)
        if (cnt == 0) continue;
        const int2* bp = bins + (size_t)n * CAP;

        float ag0[MIX], ag1[MIX];
#pragma unroll
        for (int m = 0; m < MIX; ++m) { ag0[m] = 0.f; ag1[m] = 0.f; }

        // phase 2a: aggregate
        for (int c0 = 0; c0 < cnt; c0 += 64) {
            int nb = min(64, cnt - c0);
            int idx = c0 + ((lane < nb) ? lane : 0);
            int2 es = bp[idx];
            int s_l = es.y;
#pragma unroll 8
            for (int i = 0; i < nb; ++i) {
                int s = __builtin_amdgcn_readlane(s_l, i);
                const float* wp = Wnode + (size_t)s * MIX;
                float2 x = ((const float2*)(X + (size_t)s * HIDDEN))[lane];
#pragma unroll
                for (int m = 0; m < MIX; ++m) {
                    float w = wp[m];
                    ag0[m] += x.x * w;
                    ag1[m] += x.y * w;
                }
            }
        }

#pragma unroll
        for (int m = 0; m < MIX; ++m) {
            ag0[m] = gelu_exact(ag0[m]);
            ag1[m] = gelu_exact(ag1[m]);
        }

        // phase 2b: per-edge output
        for (int c0 = 0; c0 < cnt; c0 += 64) {
            int nb = min(64, cnt - c0);
            int idx = c0 + ((lane < nb) ? lane : 0);
            int2 es = bp[idx];
            int e_l = es.x, s_l = es.y;
#pragma unroll 4
            for (int i = 0; i < nb; ++i) {
                int s = __builtin_amdgcn_readlane(s_l, i);
                int e = __builtin_amdgcn_readlane(e_l, i);
                const float* wp = Wnode + (size_t)s * MIX;
                v2f o;
                o.x = ag0[0]*wp[0] + ag0[1]*wp[1] + ag0[2]*wp[2] + ag0[3]*wp[3]
                    + ag0[4]*wp[4] + ag0[5]*wp[5] + ag0[6]*wp[6] + ag0[7]*wp[7];
                o.y = ag1[0]*wp[0] + ag1[1]*wp[1] + ag1[2]*wp[2] + ag1[3]*wp[3]
                    + ag1[4]*wp[4] + ag1[5]*wp[5] + ag1[6]*wp[6] + ag1[7]*wp[7];
                __builtin_nontemporal_store(o, (v2f*)(out_edge + (size_t)e * HIDDEN) + lane);
            }
        }
    }
}

// ---------------- fallback path (R2 kernels) ----------------
__global__ __launch_bounds__(256) void k_prep(const float* __restrict__ X,
                                              const float* __restrict__ W_A,
                                              const float* __restrict__ W_B,
                                              float* __restrict__ Wnode,
                                              const int* __restrict__ src,
                                              const int* __restrict__ dst,
                                              int* __restrict__ cursor,
                                              int2* __restrict__ bins,
                                              float* __restrict__ out_src,
                                              float* __restrict__ out_dst,
                                              int N, int E, int WB) {
    int t = threadIdx.x;
    if ((int)blockIdx.x >= WB) {
        int e = ((int)blockIdx.x - WB) * 256 + t;
        if (e < E) {
            int d = dst[e];
            int s = src[e];
            int p = atomicAdd(&cursor[d], 1);
            if (p < CAP) bins[(size_t)d * CAP + p] = make_int2(e, s);
            __builtin_nontemporal_store((float)s, &out_src[e]);
            __builtin_nontemporal_store((float)d, &out_dst[e]);
        }
        return;
    }
    __shared__ union SmemU {
        struct { float xs[NBW * LDX]; float wa[HIDDEN * LDW]; } ab;
        float gsm[NBW * LDG];
    } u;
    __shared__ float wb[MIX * LDG];
    int n0 = blockIdx.x * NBW;
    {
        int r = t >> 3;
        int c0 = (t & 7) * 16;
        int rn = n0 + r; if (rn >= N) rn = N - 1;
        const float* xp = X + (size_t)rn * HIDDEN + c0;
        float4 a = ((const float4*)xp)[0];
        float4 bb = ((const float4*)xp)[1];
        float4 c = ((const float4*)xp)[2];
        float4 d = ((const float4*)xp)[3];
        float tmp[16] = {a.x,a.y,a.z,a.w, bb.x,bb.y,bb.z,bb.w,
                         c.x,c.y,c.z,c.w, d.x,d.y,d.z,d.w};
#pragma unroll
        for (int q = 0; q < 16; ++q) u.ab.xs[r * LDX + c0 + q] = tmp[q];
    }
    int ngrp = t & 7;
    int jgrp = t >> 3;
    float acc[4][4];
#pragma unroll
    for (int i = 0; i < 4; ++i)
#pragma unroll
        for (int j = 0; j < 4; ++j) acc[i][j] = 0.f;
    for (int kt = 0; kt < HIDDEN; kt += KT) {
        __syncthreads();
        {
            int j = t >> 1;
            int c0 = (t & 1) * 8;
            const float* wp = W_A + (size_t)j * HIDDEN + kt + c0;
            float4 a = ((const float4*)wp)[0];
            float4 bb = ((const float4*)wp)[1];
            float tmp[8] = {a.x,a.y,a.z,a.w, bb.x,bb.y,bb.z,bb.w};
#pragma unroll
            for (int q = 0; q < 8; ++q) u.ab.wa[j * LDW + c0 + q] = tmp[q];
        }
        __syncthreads();
#pragma unroll
        for (int k = 0; k < KT; ++k) {
            float xv[4], wv[4];
#pragma unroll
            for (int i = 0; i < 4; ++i) xv[i] = u.ab.xs[(ngrp * 4 + i) * LDX + kt + k];
#pragma unroll
            for (int j = 0; j < 4; ++j) wv[j] = u.ab.wa[(jgrp * 4 + j) * LDW + k];
#pragma unroll
            for (int i = 0; i < 4; ++i)
#pragma unroll
                for (int j = 0; j < 4; ++j) acc[i][j] += xv[i] * wv[j];
        }
    }
    __syncthreads();
#pragma unroll
    for (int i = 0; i < 4; ++i)
#pragma unroll
        for (int j = 0; j < 4; ++j)
            u.gsm[(ngrp * 4 + i) * LDG + (jgrp * 4 + j)] = gelu_exact(acc[i][j]);
    if (t < 64) {
        int r = t >> 3;
        int c0 = (t & 7) * 16;
        const float* wp = W_B + (size_t)r * HIDDEN + c0;
        float4 a = ((const float4*)wp)[0];
        float4 bb = ((const float4*)wp)[1];
        float4 c = ((const float4*)wp)[2];
        float4 d = ((const float4*)wp)[3];
        float tmp[16] = {a.x,a.y,a.z,a.w, bb.x,bb.y,bb.z,bb.w,
                         c.x,c.y,c.z,c.w, d.x,d.y,d.z,d.w};
#pragma unroll
        for (int q = 0; q < 16; ++q) wb[r * LDG + c0 + q] = tmp[q];
    }
    __syncthreads();
    {
        int n = t >> 3;
        int m = t & 7;
        float a = 0.f;
#pragma unroll 8
        for (int k = 0; k < HIDDEN; ++k)
            a += u.gsm[n * LDG + k] * wb[m * LDG + k];
        if (n0 + n < N) Wnode[(size_t)n0 * MIX + t] = a;
    }
}

__global__ __launch_bounds__(256) void k_node(const float* __restrict__ X,
                                              const float* __restrict__ Wnode,
                                              const int2* __restrict__ bins,
                                              const int* __restrict__ cursor,
                                              float* __restrict__ out_edge,
                                              int N) {
    int lane = threadIdx.x & 63;
    int n = blockIdx.x * 4 + (threadIdx.x >> 6);
    if (n >= N) return;
    int cnt = cursor[n];
    if (cnt > CAP) cnt = CAP;
    if (cnt == 0) return;
    const int2* bp = bins + (size_t)n * CAP;
    float ag0[MIX], ag1[MIX];
#pragma unroll
    for (int m = 0; m < MIX; ++m) { ag0[m] = 0.f; ag1[m] = 0.f; }
    for (int c0 = 0; c0 < cnt; c0 += 64) {
        int nb = min(64, cnt - c0);
        int idx = c0 + ((lane < nb) ? lane : 0);
        int2 es = bp[idx];
        int s_l = es.y;
#pragma unroll 8
        for (int i = 0; i < nb; ++i) {
            int s = __builtin_amdgcn_readlane(s_l, i);
            const float* wp = Wnode + (size_t)s * MIX;
            float2 x = ((const float2*)(X + (size_t)s * HIDDEN))[lane];
#pragma unroll
            for (int m = 0; m < MIX; ++m) {
                float w = wp[m];
                ag0[m] += x.x * w;
                ag1[m] += x.y * w;
            }
        }
    }
#pragma unroll
    for (int m = 0; m < MIX; ++m) {
        ag0[m] = gelu_exact(ag0[m]);
        ag1[m] = gelu_exact(ag1[m]);
    }
    for (int c0 = 0; c0 < cnt; c0 += 64) {
        int nb = min(64, cnt - c0);
        int idx = c0 + ((lane < nb) ? lane : 0);
        int2 es = bp[idx];
        int e_l = es.x, s_l = es.y;
#pragma unroll 4
        for (int i = 0; i < nb; ++i) {
            int s = __builtin_amdgcn_readlane(s_l, i);
            int e = __builtin_amdgcn_readlane(e_l, i);
            const float* wp = Wnode + (size_t)s * MIX;
            v2f o;
            o.x = ag0[0]*wp[0] + ag0[1]*wp[1] + ag0[2]*wp[2] + ag0[3]*wp[3]
                + ag0[4]*wp[4] + ag0[5]*wp[5] + ag0[6]*wp[6] + ag0[7]*wp[7];
            o.y = ag1[0]*wp[0] + ag1[1]*wp[1] + ag1[2]*wp[2] + ag1[3]*wp[3]
                + ag1[4]*wp[4] + ag1[5]*wp[5] + ag1[6]*wp[6] + ag1[7]*wp[7];
            __builtin_nontemporal_store(o, (v2f*)(out_edge + (size_t)e * HIDDEN) + lane);
        }
    }
}

extern "C" void kernel_launch(void* const* d_in, const int* in_sizes, int n_in,
                              void* d_out, int out_size, void* d_ws, size_t ws_size,
                              hipStream_t stream) {
    const float* X   = (const float*)d_in[0];
    const float* W_A = (const float*)d_in[1];
    const float* W_B = (const float*)d_in[2];
    const int*   ei  = (const int*)d_in[3];

    int N = in_sizes[0] / HIDDEN;
    int E = in_sizes[3] / 2;
    const int* src = ei;
    const int* dst = ei + E;

    float* out      = (float*)d_out;
    float* out_edge = out;                        // (E, 128)
    float* out_src  = out + (size_t)E * HIDDEN;   // (E,)
    float* out_dst  = out_src + E;                // (E,)

    // workspace: [cursor N int][bins N*CAP int2][Wnode N*MIX float] ~10.3 MB
    int*  cursor = (int*)d_ws;
    int2* bins   = (int2*)(cursor + N);
    float* Wnode = (float*)(bins + (size_t)N * CAP);

    int WB = (N + NBW - 1) / NBW;
    int EB = (E + 255) / 256;

    // co-resident grid size for the cooperative launch (cached)
    static int g_grid = 0;
    if (g_grid == 0) {
        int bpc = 0;
        hipOccupancyMaxActiveBlocksPerMultiprocessor(&bpc, k_fused, 256, 0);
        int ncu = 0;
        hipDeviceProp_t prop;
        if (hipGetDeviceProperties(&prop, 0) == hipSuccess)
            ncu = prop.multiProcessorCount;
        if (ncu <= 0) ncu = 256;
        if (bpc <= 0) bpc = 1;
        g_grid = bpc * ncu;
        if (g_grid <= WB) g_grid = WB + 256;  // paranoia: keep hist blocks
    }

    void* args[] = {(void*)&X, (void*)&W_A, (void*)&W_B, (void*)&src, (void*)&dst,
                    (void*)&Wnode, (void*)&cursor, (void*)&bins,
                    (void*)&out_src, (void*)&out_dst, (void*)&out_edge,
                    (void*)&N, (void*)&E, (void*)&WB};
    hipError_t err = hipLaunchCooperativeKernel((void*)k_fused, dim3(g_grid),
                                                dim3(256), args, 0, stream);
    if (err != hipSuccess) {
        // fallback: proven 3-dispatch chain
        hipMemsetAsync(cursor, 0, sizeof(int) * (size_t)N, stream);
        k_prep<<<WB + EB, 256, 0, stream>>>(X, W_A, W_B, Wnode, src, dst,
                                            cursor, bins, out_src, out_dst, N, E, WB);
        k_node<<<(N + 3) / 4, 256, 0, stream>>>(X, Wnode, bins, cursor, out_edge, N);
    }
}

// Round 4
// 250.034 us; speedup vs baseline: 1.7344x; 1.7344x over previous
//
#include <hip/hip_runtime.h>

#define HIDDEN 128
#define MIX 8
#define CAP 128   // bin capacity per node; degrees ~Poisson(32), max@N=10k ~65

// ---- k_prep (Wnode path) tiling params ----
#define NBW 32   // nodes per block
#define LDX 33   // xs row stride
#define KT  16   // k-slab width for W_A
#define LDW 17   // wa slab row stride
#define LDG 132  // gsm/wb row stride (132%32=4, float4-aligned)

typedef float v2f __attribute__((ext_vector_type(2)));

__device__ __forceinline__ float gelu_exact(float x) {
    return 0.5f * x * (1.0f + erff(x * 0.7071067811865476f));
}

// L1 (merged): blocks [0, WB) compute Wnode; blocks [WB, WB+EB) histogram+bin
// edges directly into fixed-capacity per-node bins and echo src/dst.
// LDS: union{ {xs,wa} , gsm } + wb = 20.6 KB -> 7 blocks/CU.
__global__ __launch_bounds__(256) void k_prep(const float* __restrict__ X,
                                              const float* __restrict__ W_A,
                                              const float* __restrict__ W_B,
                                              float* __restrict__ Wnode,
                                              const int* __restrict__ src,
                                              const int* __restrict__ dst,
                                              int* __restrict__ cursor,
                                              int2* __restrict__ bins,
                                              float* __restrict__ out_src,
                                              float* __restrict__ out_dst,
                                              int N, int E, int WB) {
    int t = threadIdx.x;

    if ((int)blockIdx.x >= WB) {
        // ---- histogram + direct bin fill + echo ----
        int e = ((int)blockIdx.x - WB) * 256 + t;
        if (e < E) {
            int d = dst[e];
            int s = src[e];
            int p = atomicAdd(&cursor[d], 1);
            if (p < CAP) bins[(size_t)d * CAP + p] = make_int2(e, s);
            __builtin_nontemporal_store((float)s, &out_src[e]);
            __builtin_nontemporal_store((float)d, &out_dst[e]);
        }
        return;
    }

    // ---- Wnode path: Wnode[n][m] = sum_k gelu(X[n]·W_A[k,:]) * W_B[m][k] ----
    __shared__ union SmemU {
        struct { float xs[NBW * LDX]; float wa[HIDDEN * LDW]; } ab;
        float gsm[NBW * LDG];
    } u;
    __shared__ float wb[MIX * LDG];

    int n0 = blockIdx.x * NBW;

    {   // stage X rows: r = t>>3 (0..31), cols (t&7)*16 .. +15
        int r = t >> 3;
        int c0 = (t & 7) * 16;
        int rn = n0 + r; if (rn >= N) rn = N - 1;
        const float* xp = X + (size_t)rn * HIDDEN + c0;
        float4 a = ((const float4*)xp)[0];
        float4 bb = ((const float4*)xp)[1];
        float4 c = ((const float4*)xp)[2];
        float4 d = ((const float4*)xp)[3];
        float tmp[16] = {a.x,a.y,a.z,a.w, bb.x,bb.y,bb.z,bb.w,
                         c.x,c.y,c.z,c.w, d.x,d.y,d.z,d.w};
#pragma unroll
        for (int q = 0; q < 16; ++q) u.ab.xs[r * LDX + c0 + q] = tmp[q];
    }

    int ngrp = t & 7;    // 8 groups x 4 nodes
    int jgrp = t >> 3;   // 32 groups x 4 j
    float acc[4][4];
#pragma unroll
    for (int i = 0; i < 4; ++i)
#pragma unroll
        for (int j = 0; j < 4; ++j) acc[i][j] = 0.f;

    for (int kt = 0; kt < HIDDEN; kt += KT) {
        __syncthreads();  // protect wa (and xs on first iter)
        {   // stage W_A slab: j = t>>1 (0..127), cols kt + (t&1)*8 .. +7
            int j = t >> 1;
            int c0 = (t & 1) * 8;
            const float* wp = W_A + (size_t)j * HIDDEN + kt + c0;
            float4 a = ((const float4*)wp)[0];
            float4 bb = ((const float4*)wp)[1];
            float tmp[8] = {a.x,a.y,a.z,a.w, bb.x,bb.y,bb.z,bb.w};
#pragma unroll
            for (int q = 0; q < 8; ++q) u.ab.wa[j * LDW + c0 + q] = tmp[q];
        }
        __syncthreads();
#pragma unroll
        for (int k = 0; k < KT; ++k) {
            float xv[4], wv[4];
#pragma unroll
            for (int i = 0; i < 4; ++i) xv[i] = u.ab.xs[(ngrp * 4 + i) * LDX + kt + k];
#pragma unroll
            for (int j = 0; j < 4; ++j) wv[j] = u.ab.wa[(jgrp * 4 + j) * LDW + k];
#pragma unroll
            for (int i = 0; i < 4; ++i)
#pragma unroll
                for (int j = 0; j < 4; ++j) acc[i][j] += xv[i] * wv[j];
        }
    }
    __syncthreads();  // xs/wa reads done; gsm aliases them

    // gelu -> gsm[n][j]
#pragma unroll
    for (int i = 0; i < 4; ++i)
#pragma unroll
        for (int j = 0; j < 4; ++j)
            u.gsm[(ngrp * 4 + i) * LDG + (jgrp * 4 + j)] = gelu_exact(acc[i][j]);

    // stage W_B (8 x 128)
    if (t < 64) {
        int r = t >> 3;
        int c0 = (t & 7) * 16;
        const float* wp = W_B + (size_t)r * HIDDEN + c0;
        float4 a = ((const float4*)wp)[0];
        float4 bb = ((const float4*)wp)[1];
        float4 c = ((const float4*)wp)[2];
        float4 d = ((const float4*)wp)[3];
        float tmp[16] = {a.x,a.y,a.z,a.w, bb.x,bb.y,bb.z,bb.w,
                         c.x,c.y,c.z,c.w, d.x,d.y,d.z,d.w};
#pragma unroll
        for (int q = 0; q < 16; ++q) wb[r * LDG + c0 + q] = tmp[q];
    }
    __syncthreads();

    // phase B: thread t -> n = t>>3, m = t&7
    {
        int n = t >> 3;
        int m = t & 7;
        float a = 0.f;
#pragma unroll 8
        for (int k = 0; k < HIDDEN; ++k)
            a += u.gsm[n * LDG + k] * wb[m * LDG + k];
        if (n0 + n < N) Wnode[(size_t)n0 * MIX + t] = a;
    }
}

// L2: wave-per-node. Lane owns h = 2*lane, 2*lane+1; 16 accumulators in VGPRs.
// Per 64-edge chunk: each lane VECTOR-gathers its edge's Wnode row (32 B) into
// a wave-private LDS slab; the broadcast loop reads w via ds_read_b128 at a
// wave-uniform address (LDS broadcast, conflict-free). This removes the
// per-edge data-dependent s_load_dwordx8 that thrashed the scalar cache
// (R3 counters: VALUBusy 9.8% at 43% occupancy = all waves in lgkmcnt stalls).
// out_edge stores nontemporal (164 MB stream must not evict X/Wnode from L2).
__global__ __launch_bounds__(256) void k_node(const float* __restrict__ X,
                                              const float* __restrict__ Wnode,
                                              const int2* __restrict__ bins,
                                              const int* __restrict__ cursor,
                                              float* __restrict__ out_edge,
                                              int N) {
    __shared__ __align__(16) float wsm[4 * 64 * 8];  // 8 KB: 4 waves x 64 edges x 8 w
    int t = threadIdx.x;
    int lane = t & 63;
    float* ws = wsm + (t >> 6) * (64 * 8);   // wave-private; no barriers needed

    int n = blockIdx.x * 4 + (t >> 6);
    if (n >= N) return;
    int cnt = cursor[n];
    if (cnt > CAP) cnt = CAP;   // overflow guard (unreachable for this dist)
    if (cnt == 0) return;
    const int2* bp = bins + (size_t)n * CAP;

    float ag0[MIX], ag1[MIX];
#pragma unroll
    for (int m = 0; m < MIX; ++m) { ag0[m] = 0.f; ag1[m] = 0.f; }

    // ---- phase 1: aggregate ----
    for (int c0 = 0; c0 < cnt; c0 += 64) {
        int nb = min(64, cnt - c0);
        int idx = c0 + ((lane < nb) ? lane : 0);
        int2 es = bp[idx];
        int s_l = es.y;
        {   // stage Wnode rows for this chunk (vector path, one row per lane)
            const float4* wv = (const float4*)(Wnode + (size_t)s_l * MIX);
            float4 wlo = wv[0];
            float4 whi = wv[1];
            float4* wd = (float4*)(ws + (lane << 3));
            wd[0] = wlo; wd[1] = whi;
        }
#pragma unroll 8
        for (int i = 0; i < nb; ++i) {
            int s = __builtin_amdgcn_readlane(s_l, i);
            float2 x = ((const float2*)(X + (size_t)s * HIDDEN))[lane];
            const float4* wr = (const float4*)(ws + (i << 3));  // uniform addr -> broadcast
            float4 w0 = wr[0];
            float4 w1 = wr[1];
            ag0[0] += x.x * w0.x; ag0[1] += x.x * w0.y;
            ag0[2] += x.x * w0.z; ag0[3] += x.x * w0.w;
            ag0[4] += x.x * w1.x; ag0[5] += x.x * w1.y;
            ag0[6] += x.x * w1.z; ag0[7] += x.x * w1.w;
            ag1[0] += x.y * w0.x; ag1[1] += x.y * w0.y;
            ag1[2] += x.y * w0.z; ag1[3] += x.y * w0.w;
            ag1[4] += x.y * w1.x; ag1[5] += x.y * w1.y;
            ag1[6] += x.y * w1.z; ag1[7] += x.y * w1.w;
        }
    }

#pragma unroll
    for (int m = 0; m < MIX; ++m) {
        ag0[m] = gelu_exact(ag0[m]);
        ag1[m] = gelu_exact(ag1[m]);
    }

    // ---- phase 2: per-edge output ----
    for (int c0 = 0; c0 < cnt; c0 += 64) {
        int nb = min(64, cnt - c0);
        int idx = c0 + ((lane < nb) ? lane : 0);
        int2 es = bp[idx];
        int e_l = es.x, s_l = es.y;
        {   // restage Wnode rows for this chunk
            const float4* wv = (const float4*)(Wnode + (size_t)s_l * MIX);
            float4 wlo = wv[0];
            float4 whi = wv[1];
            float4* wd = (float4*)(ws + (lane << 3));
            wd[0] = wlo; wd[1] = whi;
        }
#pragma unroll 4
        for (int i = 0; i < nb; ++i) {
            int e = __builtin_amdgcn_readlane(e_l, i);
            const float4* wr = (const float4*)(ws + (i << 3));  // uniform addr -> broadcast
            float4 w0 = wr[0];
            float4 w1 = wr[1];
            v2f o;
            o.x = ag0[0]*w0.x + ag0[1]*w0.y + ag0[2]*w0.z + ag0[3]*w0.w
                + ag0[4]*w1.x + ag0[5]*w1.y + ag0[6]*w1.z + ag0[7]*w1.w;
            o.y = ag1[0]*w0.x + ag1[1]*w0.y + ag1[2]*w0.z + ag1[3]*w0.w
                + ag1[4]*w1.x + ag1[5]*w1.y + ag1[6]*w1.z + ag1[7]*w1.w;
            __builtin_nontemporal_store(o, (v2f*)(out_edge + (size_t)e * HIDDEN) + lane);
        }
    }
}

extern "C" void kernel_launch(void* const* d_in, const int* in_sizes, int n_in,
                              void* d_out, int out_size, void* d_ws, size_t ws_size,
                              hipStream_t stream) {
    const float* X   = (const float*)d_in[0];
    const float* W_A = (const float*)d_in[1];
    const float* W_B = (const float*)d_in[2];
    const int*   ei  = (const int*)d_in[3];

    const int N = in_sizes[0] / HIDDEN;
    const int E = in_sizes[3] / 2;
    const int* src = ei;
    const int* dst = ei + E;

    float* out      = (float*)d_out;
    float* out_edge = out;                        // (E, 128)
    float* out_src  = out + (size_t)E * HIDDEN;   // (E,)
    float* out_dst  = out_src + E;                // (E,)

    // workspace: [cursor N int][bins N*CAP int2][Wnode N*MIX float] ~10.3 MB
    int*  cursor = (int*)d_ws;
    int2* bins   = (int2*)(cursor + N);
    float* Wnode = (float*)(bins + (size_t)N * CAP);

    hipMemsetAsync(cursor, 0, sizeof(int) * (size_t)N, stream);

    int WB = (N + NBW - 1) / NBW;
    int EB = (E + 255) / 256;

    k_prep<<<WB + EB, 256, 0, stream>>>(X, W_A, W_B, Wnode, src, dst,
                                        cursor, bins, out_src, out_dst, N, E, WB);
    k_node<<<(N + 3) / 4, 256, 0, stream>>>(X, Wnode, bins, cursor, out_edge, N);
}